// Round 3
// baseline (7025.395 us; speedup 1.0000x reference)
//
#include <hip/hip_runtime.h>
#include <hip/hip_bf16.h>
#include <stdint.h>

#define BATCH 1024
#define DIM   1024
#define HID   4096
#define TPTS  16

typedef __attribute__((ext_vector_type(8))) short  short8;
typedef __attribute__((ext_vector_type(4))) float  floatx4;

__device__ __forceinline__ unsigned short f32_to_bf16_bits(float f) {
    union { float f; unsigned u; } v; v.f = f;
    return (unsigned short)((v.u + 0x7fffu + ((v.u >> 16) & 1u)) >> 16);
}

__device__ __forceinline__ void store_bf16x4(unsigned short* p, floatx4 v) {
    union { unsigned short u[4]; uint2 q; } pk;
    pk.u[0] = f32_to_bf16_bits(v[0]);
    pk.u[1] = f32_to_bf16_bits(v[1]);
    pk.u[2] = f32_to_bf16_bits(v[2]);
    pk.u[3] = f32_to_bf16_bits(v[3]);
    *(uint2*)p = pk.q;
}

// fast tanh: 1 - 2/(e^{2x}+1); saturates correctly for |x| large
__device__ __forceinline__ float fast_tanh(float x) {
    float e = __expf(2.0f * x);
    return 1.0f - 2.0f / (e + 1.0f);
}

// async 16B global -> LDS (DMA). LDS dest = wave-uniform base + lane*16.
__device__ __forceinline__ void g2l16(const unsigned short* g, char* l) {
    __builtin_amdgcn_global_load_lds(
        (const __attribute__((address_space(1))) void*)g,
        (__attribute__((address_space(3))) void*)l, 16, 0, 0);
}

// C[M,N] tile = A[M,K] @ B[K,N]; A row-major bf16 (lda), Bt=B^T row-major (ldb).
// Tile 64(M) x 128(N), BK=64, 4 waves each 64x32. 512-block grids -> 2 blocks/CU.
// MODE 1: Hbf = bf16(tanh(acc + bias[n])), coalesced store via LDS restage.
// MODE 0: split-K partial (z = K-chunk) -> fp32 parts; LAST arriver per tile
//         (device-scope counter) sums 4 partials + b2 and does the fused RK4
//         state update (combine) for its 64x128 tile.
template<int MODE>
__global__ __launch_bounds__(256, 2)
void gemm_bt(const unsigned short* __restrict__ A,
             const unsigned short* __restrict__ Bt,
             const float* __restrict__ bias,
             void* __restrict__ Cout,
             int lda, int ldb, int ldc, int K,
             const float* __restrict__ b2,
             const float* __restrict__ ycur,
             const float* __restrict__ tspan,
             int step, int mode, int evalIdx,
             int* __restrict__ cnt,
             float* __restrict__ kacc,
             unsigned short* __restrict__ ybf,
             float* __restrict__ ynext)
{
    // sA: [64 rows][128B] = 8KB @0; sB: [128 rows][128B] = 16KB @8192.
    // Row = 8 chunks of 16B; chunk ch holds global k-chunk ch ^ (row & 7).
    __shared__ __align__(16) char smem[24576];
    char* sA = smem;
    char* sB = smem + 8192;

    const int tid  = threadIdx.x;
    const int wave = tid >> 6;
    const int lane = tid & 63;
    const int wn = wave * 32;          // wave col offset in tile
    const int lr = lane & 15;
    const int q  = lane >> 4;

    const int rowBase = blockIdx.y * 64;
    const int colBase = blockIdx.x * 128;
    const long long koff = (long long)blockIdx.z * K;

    // staging: 24KB / (256 thr * 16B) = 6 calls; j=0..1 -> sA, j=2..5 -> sB
    const unsigned short* gp[6];
    char* lp[6];
#pragma unroll
    for (int j = 0; j < 6; ++j) {
        const int p  = (j * 256 + tid) * 16;   // byte pos in 24KB
        const int pa = (j < 2) ? p : (p - 8192);
        const int row = pa >> 7;
        const int ch  = (pa >> 4) & 7;
        const int sc  = ch ^ (row & 7);
        if (j < 2)
            gp[j] = A + (long long)(rowBase + row) * lda + koff + sc * 8;
        else
            gp[j] = Bt + (long long)(colBase + row) * ldb + koff + sc * 8;
        lp[j] = smem + p;
    }

    floatx4 acc[4][2];
#pragma unroll
    for (int mi = 0; mi < 4; ++mi)
#pragma unroll
        for (int ni = 0; ni < 2; ++ni) {
            floatx4 z4 = {0.f, 0.f, 0.f, 0.f};
            acc[mi][ni] = z4;
        }

    const int xr = lr & 7;
    int aOff[4], bOff[2];
#pragma unroll
    for (int i = 0; i < 4; ++i) aOff[i] = (i * 16 + lr) * 128;
#pragma unroll
    for (int i = 0; i < 2; ++i) bOff[i] = (wn + i * 16 + lr) * 128;
    const int swz0 = ((0 + q) ^ xr) * 16;
    const int swz1 = ((4 + q) ^ xr) * 16;

    const int KB = K >> 6;  // BK = 64
    for (int kb = 0; kb < KB; ++kb) {
        if (kb) __syncthreads();
        const int kadv = kb * 64;
#pragma unroll
        for (int j = 0; j < 6; ++j)
            g2l16(gp[j] + kadv, lp[j]);
        __syncthreads();

        short8 af[4][2], bfr[2][2];
#pragma unroll
        for (int i = 0; i < 4; ++i) {
            af[i][0] = *(const short8*)(sA + aOff[i] + swz0);
            af[i][1] = *(const short8*)(sA + aOff[i] + swz1);
        }
#pragma unroll
        for (int i = 0; i < 2; ++i) {
            bfr[i][0] = *(const short8*)(sB + bOff[i] + swz0);
            bfr[i][1] = *(const short8*)(sB + bOff[i] + swz1);
        }
#pragma unroll
        for (int g = 0; g < 2; ++g)
#pragma unroll
            for (int mi = 0; mi < 4; ++mi)
#pragma unroll
                for (int ni = 0; ni < 2; ++ni)
                    acc[mi][ni] = __builtin_amdgcn_mfma_f32_16x16x32_bf16(
                        af[mi][g], bfr[ni][g], acc[mi][ni], 0, 0, 0);
    }

    if (MODE == 1) {
        __syncthreads();  // done reading sA/sB; reuse smem as sC
        float bias2[2];
#pragma unroll
        for (int ni = 0; ni < 2; ++ni)
            bias2[ni] = bias[colBase + wn + ni * 16 + lr];
        unsigned short* sC = (unsigned short*)smem;  // [64][136] bf16
#pragma unroll
        for (int mi = 0; mi < 4; ++mi)
#pragma unroll
            for (int ni = 0; ni < 2; ++ni)
#pragma unroll
                for (int r = 0; r < 4; ++r) {
                    const int row = mi * 16 + q * 4 + r;
                    const int col = wn + ni * 16 + lr;
                    sC[row * 136 + col] =
                        f32_to_bf16_bits(fast_tanh(acc[mi][ni][r] + bias2[ni]));
                }
        __syncthreads();
        unsigned short* C = (unsigned short*)Cout;
#pragma unroll
        for (int it = 0; it < 4; ++it) {
            const int row = it * 16 + (tid >> 4);
            const int cc  = (tid & 15) * 8;
            *(uint4*)(C + (long long)(rowBase + row) * ldc + colBase + cc) =
                *(const uint4*)(sC + row * 136 + cc);
        }
    } else {
        // split-K partial store
        float* C = (float*)Cout + (long long)blockIdx.z * (BATCH * DIM);
#pragma unroll
        for (int mi = 0; mi < 4; ++mi)
#pragma unroll
            for (int ni = 0; ni < 2; ++ni) {
                const int r0 = rowBase + mi * 16 + q * 4;
                const int c  = colBase + wn + ni * 16 + lr;
#pragma unroll
                for (int r = 0; r < 4; ++r)
                    C[(long long)(r0 + r) * ldc + c] = acc[mi][ni][r];
            }
        // device-scope release, then bump this tile's arrival counter
        __threadfence();
        __syncthreads();
        __shared__ int sOld;
        if (tid == 0)
            sOld = atomicAdd(&cnt[blockIdx.y * 8 + blockIdx.x], 1);
        __syncthreads();
        if (sOld == 4 * evalIdx + 3) {
            // we are the last of the 4 split-K blocks: acquire + combine
            __threadfence();
            const float h = tspan[step + 1] - tspan[step];
            const int NV4 = BATCH * DIM / 4;
            const floatx4* P = (const floatx4*)Cout;
#pragma unroll
            for (int u = 0; u < 8; ++u) {
                const int idx4 = u * 256 + tid;          // float4 idx in tile
                const int row  = (idx4 * 4) >> 7;        // 0..63
                const int col  = (idx4 * 4) & 127;
                const long long g4 =
                    (((long long)(rowBase + row) * DIM) + colBase + col) >> 2;
                floatx4 k = P[g4] + P[g4 + NV4] + P[g4 + 2 * NV4] + P[g4 + 3 * NV4];
                k = k + *(const floatx4*)(b2 + colBase + col);
                floatx4 y = ((const floatx4*)ycur)[g4];
                floatx4* ka = (floatx4*)kacc;
                if (mode == 1) {
                    ka[g4] = k;
                    store_bf16x4(ybf + g4 * 4, y + (0.5f * h) * k);
                } else if (mode == 2) {
                    ka[g4] = ka[g4] + 2.0f * k;
                    store_bf16x4(ybf + g4 * 4, y + (0.5f * h) * k);
                } else if (mode == 3) {
                    ka[g4] = ka[g4] + 2.0f * k;
                    store_bf16x4(ybf + g4 * 4, y + h * k);
                } else {
                    floatx4 yn = y + (h * (1.0f / 6.0f)) * (ka[g4] + k);
                    ((floatx4*)ynext)[g4] = yn;
                    store_bf16x4(ybf + g4 * 4, yn);
                }
            }
        }
    }
}

// out[c][r] = bf16(in[r][c]); in is R x C fp32.
__global__ void transpose_cast(const float* __restrict__ in,
                               unsigned short* __restrict__ out, int R, int C)
{
    __shared__ float tile[32][33];
    const int bx = blockIdx.x * 32;
    const int by = blockIdx.y * 32;
    const int tx = threadIdx.x, ty = threadIdx.y;  // (32, 8)
#pragma unroll
    for (int i = 0; i < 4; ++i)
        tile[ty + i * 8][tx] = in[(long long)(by + ty + i * 8) * C + bx + tx];
    __syncthreads();
#pragma unroll
    for (int i = 0; i < 4; ++i)
        out[(long long)(bx + ty + i * 8) * R + by + tx] =
            f32_to_bf16_bits(tile[tx][ty + i * 8]);
}

// d_out[0:16] = t_span; traj[0] = y_init; ybf = bf16(y_init)
__global__ void init_kernel(const float* __restrict__ y0,
                            const float* __restrict__ tspan,
                            float* __restrict__ out,
                            unsigned short* __restrict__ ybf)
{
    const int i = blockIdx.x * blockDim.x + threadIdx.x;
    floatx4 v = ((const floatx4*)y0)[i];
    ((floatx4*)(out + TPTS))[i] = v;
    store_bf16x4(ybf + i * 4, v);
    if (blockIdx.x == 0 && threadIdx.x < TPTS) out[threadIdx.x] = tspan[threadIdx.x];
}

extern "C" void kernel_launch(void* const* d_in, const int* in_sizes, int n_in,
                              void* d_out, int out_size, void* d_ws, size_t ws_size,
                              hipStream_t stream)
{
    (void)in_sizes; (void)n_in; (void)out_size; (void)ws_size;
    const float* y0    = (const float*)d_in[0];
    const float* tspan = (const float*)d_in[1];
    const float* W1    = (const float*)d_in[2];
    const float* b1    = (const float*)d_in[3];
    const float* W2    = (const float*)d_in[4];
    const float* b2    = (const float*)d_in[5];
    float* out = (float*)d_out;

    char* ws = (char*)d_ws;
    unsigned short* W1T = (unsigned short*)(ws);                // [HID][DIM] bf16   8MB
    unsigned short* W2T = (unsigned short*)(ws + (8ll << 20));  // [DIM][HID] bf16   8MB
    unsigned short* Ybf = (unsigned short*)(ws + (16ll << 20)); // [BATCH][DIM] bf16 2MB
    unsigned short* Hbf = (unsigned short*)(ws + (18ll << 20)); // [BATCH][HID] bf16 8MB
    float* parts = (float*)(ws + (26ll << 20));                 // [4][BATCH][DIM]  16MB
    float* kacc  = (float*)(ws + (42ll << 20));                 // [BATCH][DIM]      4MB
    int*   cnt   = (int*)(ws + (46ll << 20));                   // [128] tile counters

    hipMemsetAsync(cnt, 0, 128 * sizeof(int), stream);

    dim3 tb(32, 8);
    transpose_cast<<<dim3(HID / 32, DIM / 32), tb, 0, stream>>>(W1, W1T, DIM, HID);
    transpose_cast<<<dim3(DIM / 32, HID / 32), tb, 0, stream>>>(W2, W2T, HID, DIM);
    init_kernel<<<BATCH * DIM / 1024, 256, 0, stream>>>(y0, tspan, out, Ybf);

    float* traj = out + TPTS;
    for (int t = 0; t < TPTS - 1; ++t) {
        const float* ycur = traj + (long long)t * BATCH * DIM;
        float* ynext = traj + (long long)(t + 1) * BATCH * DIM;
        for (int e = 0; e < 4; ++e) {
            // H = tanh(Y @ W1 + b1) -> bf16 [BATCH][HID]; 512 blocks
            gemm_bt<1><<<dim3(HID / 128, BATCH / 64, 1), 256, 0, stream>>>(
                Ybf, W1T, b1, (void*)Hbf, DIM, DIM, HID, DIM,
                nullptr, nullptr, nullptr, 0, 0, 0, nullptr, nullptr, nullptr, nullptr);
            // parts[z] = H[:,z*1024:+1024] @ W2[z*1024:+1024,:]; 512 blocks;
            // last split-K arriver per tile does fused combine + RK4 update
            gemm_bt<0><<<dim3(DIM / 128, BATCH / 64, 4), 256, 0, stream>>>(
                Hbf, W2T, nullptr, (void*)parts, HID, HID, DIM, HID / 4,
                b2, ycur, tspan, t, e + 1, t * 4 + e, cnt, kacc, Ybf, ynext);
        }
    }
}

// Round 4
// 2899.792 us; speedup vs baseline: 2.4227x; 2.4227x over previous
//
#include <hip/hip_runtime.h>
#include <hip/hip_bf16.h>
#include <stdint.h>

#define BATCH 1024
#define DIM   1024
#define HID   4096
#define TPTS  16

typedef __attribute__((ext_vector_type(8))) short  short8;
typedef __attribute__((ext_vector_type(4))) float  floatx4;

__device__ __forceinline__ unsigned short f32_to_bf16_bits(float f) {
    union { float f; unsigned u; } v; v.f = f;
    return (unsigned short)((v.u + 0x7fffu + ((v.u >> 16) & 1u)) >> 16);
}

__device__ __forceinline__ void store_bf16x4(unsigned short* p, floatx4 v) {
    union { unsigned short u[4]; uint2 q; } pk;
    pk.u[0] = f32_to_bf16_bits(v[0]);
    pk.u[1] = f32_to_bf16_bits(v[1]);
    pk.u[2] = f32_to_bf16_bits(v[2]);
    pk.u[3] = f32_to_bf16_bits(v[3]);
    *(uint2*)p = pk.q;
}

// fast tanh: 1 - 2/(e^{2x}+1); saturates correctly for |x| large
__device__ __forceinline__ float fast_tanh(float x) {
    float e = __expf(2.0f * x);
    return 1.0f - 2.0f / (e + 1.0f);
}

// async 16B global -> LDS DMA. HW dest = wave-uniform base + lane*16;
// our lds ptr is linear in tid so this holds per-wave.
__device__ __forceinline__ void g2l16(const unsigned short* g, char* l) {
    __builtin_amdgcn_global_load_lds(
        (const __attribute__((address_space(1))) void*)g,
        (__attribute__((address_space(3))) void*)l, 16, 0, 0);
}

// C[M,N] = A[M,K] @ B[K,N]; A row-major bf16 (lda), Bt=B^T row-major bf16 (ldb).
// 128x128 tile, BK=128 (64KB LDS), 4 waves in 2x2 of 64x64.
// Row = 256B = 16 chunks of 16B; chunk ch holds global k-chunk ch ^ (row & 15)
// -> conflict-free HW staging writes AND <=2-way (free) ds_read_b128.
// MODE 0: fp32 out, no bias (split-K partial; z selects K-chunk)
// MODE 1: bf16 out = tanh(acc + bias[n]), coalesced store via LDS restage
template<int MODE>
__global__ __launch_bounds__(256, 1)
void gemm_bt(const unsigned short* __restrict__ A,
             const unsigned short* __restrict__ Bt,
             const float* __restrict__ bias,
             void* __restrict__ Cout,
             int lda, int ldb, int ldc, int K, long long partStride)
{
    __shared__ __align__(16) char smem[65536];  // sA 32KB @0, sB 32KB @32768
    char* sA = smem;
    char* sB = smem + 32768;

    const int tid  = threadIdx.x;
    const int wave = tid >> 6;
    const int lane = tid & 63;
    const int wm = (wave >> 1) * 64;
    const int wn = (wave & 1) * 64;
    const int lr = lane & 15;
    const int q  = lane >> 4;

    const int rowBase = blockIdx.y * 128;
    const int colBase = blockIdx.x * 128;
    const long long koff = (long long)blockIdx.z * K;

    // staging: 64KB / (256 thr * 16B) = 16 passes; j=0..7 -> sA, 8..15 -> sB.
    // pass j covers rows j*16 .. j*16+15 of its region (16 tids per row).
    const int srow0 = tid >> 4;           // 0..15: row within a pass
    const int sch   = tid & 15;           // chunk slot within row
    const int ssc   = sch ^ (srow0 & 15); // swizzled global k-chunk
    const unsigned short* gA = A + (long long)(rowBase + srow0) * lda + koff + ssc * 8;
    const unsigned short* gB = Bt + (long long)(colBase + srow0) * ldb + koff + ssc * 8;
    char* lA = sA + tid * 16;             // pass j adds j*4096
    char* lB = sB + tid * 16;

    floatx4 acc[4][4];
#pragma unroll
    for (int mi = 0; mi < 4; ++mi)
#pragma unroll
        for (int ni = 0; ni < 4; ++ni) {
            floatx4 z4 = {0.f, 0.f, 0.f, 0.f};
            acc[mi][ni] = z4;
        }

    int aOff[4], bOff[4];
#pragma unroll
    for (int i = 0; i < 4; ++i) {
        aOff[i] = (wm + i * 16 + lr) * 256;
        bOff[i] = (wn + i * 16 + lr) * 256;
    }

    const int KB = K >> 7;  // BK = 128
    for (int kb = 0; kb < KB; ++kb) {
        if (kb) __syncthreads();
        const long long kadv = (long long)kb * 128;
#pragma unroll
        for (int j = 0; j < 8; ++j)
            g2l16(gA + (long long)j * 16 * lda + kadv, lA + j * 4096);
#pragma unroll
        for (int j = 0; j < 8; ++j)
            g2l16(gB + (long long)j * 16 * ldb + kadv, lB + j * 4096);
        __syncthreads();

#pragma unroll
        for (int g = 0; g < 4; ++g) {
            const int swz = ((g * 4 + q) ^ lr) * 16;
            short8 af[4], bfr[4];
#pragma unroll
            for (int i = 0; i < 4; ++i) {
                af[i]  = *(const short8*)(sA + aOff[i] + swz);
                bfr[i] = *(const short8*)(sB + bOff[i] + swz);
            }
#pragma unroll
            for (int mi = 0; mi < 4; ++mi)
#pragma unroll
                for (int ni = 0; ni < 4; ++ni)
                    acc[mi][ni] = __builtin_amdgcn_mfma_f32_16x16x32_bf16(
                        af[mi], bfr[ni], acc[mi][ni], 0, 0, 0);
        }
    }

    if (MODE == 0) {
        float* C = (float*)Cout + (long long)blockIdx.z * partStride;
#pragma unroll
        for (int mi = 0; mi < 4; ++mi)
#pragma unroll
            for (int ni = 0; ni < 4; ++ni) {
                const int r0 = rowBase + wm + mi * 16 + q * 4;
                const int c  = colBase + wn + ni * 16 + lr;
#pragma unroll
                for (int r = 0; r < 4; ++r)
                    C[(long long)(r0 + r) * ldc + c] = acc[mi][ni][r];
            }
    } else {
        __syncthreads();  // done reading sA/sB; reuse smem as sC
        float bias4[4];
#pragma unroll
        for (int ni = 0; ni < 4; ++ni)
            bias4[ni] = bias[colBase + wn + ni * 16 + lr];
        unsigned short* sC = (unsigned short*)smem;  // [128][136] bf16
#pragma unroll
        for (int mi = 0; mi < 4; ++mi)
#pragma unroll
            for (int ni = 0; ni < 4; ++ni)
#pragma unroll
                for (int r = 0; r < 4; ++r) {
                    const int row = wm + mi * 16 + q * 4 + r;
                    const int col = wn + ni * 16 + lr;
                    sC[row * 136 + col] =
                        f32_to_bf16_bits(fast_tanh(acc[mi][ni][r] + bias4[ni]));
                }
        __syncthreads();
        unsigned short* C = (unsigned short*)Cout;
#pragma unroll
        for (int it = 0; it < 8; ++it) {
            const int row = it * 16 + (tid >> 4);
            const int cc  = (tid & 15) * 8;
            *(uint4*)(C + (long long)(rowBase + row) * ldc + colBase + cc) =
                *(const uint4*)(sC + row * 136 + cc);
        }
    }
}

// k = sum_z parts[z] + b2;  RK4 state update + bf16 cast of next matmul input.
__global__ void combine(const float* __restrict__ parts,
                        const float* __restrict__ b2,
                        const float* __restrict__ ycur,
                        const float* __restrict__ tspan,
                        int step, int mode,
                        float* __restrict__ kacc,
                        unsigned short* __restrict__ ybf,
                        float* __restrict__ ynext)
{
    const int i = blockIdx.x * blockDim.x + threadIdx.x;  // over BATCH*DIM/4
    const float h = tspan[step + 1] - tspan[step];
    const int NV = BATCH * DIM / 4;
    const floatx4* p = (const floatx4*)parts;
    floatx4 k = p[i] + p[i + NV] + p[i + 2 * NV] + p[i + 3 * NV];
    k = k + *(const floatx4*)(b2 + ((i * 4) & (DIM - 1)));
    floatx4 y = ((const floatx4*)ycur)[i];
    floatx4* ka = (floatx4*)kacc;
    if (mode == 1) {
        ka[i] = k;
        store_bf16x4(ybf + i * 4, y + (0.5f * h) * k);
    } else if (mode == 2) {
        ka[i] = ka[i] + 2.0f * k;
        store_bf16x4(ybf + i * 4, y + (0.5f * h) * k);
    } else if (mode == 3) {
        ka[i] = ka[i] + 2.0f * k;
        store_bf16x4(ybf + i * 4, y + h * k);
    } else {
        floatx4 yn = y + (h * (1.0f / 6.0f)) * (ka[i] + k);
        ((floatx4*)ynext)[i] = yn;
        store_bf16x4(ybf + i * 4, yn);
    }
}

// out[c][r] = bf16(in[r][c]); in is R x C fp32.
__global__ void transpose_cast(const float* __restrict__ in,
                               unsigned short* __restrict__ out, int R, int C)
{
    __shared__ float tile[32][33];
    const int bx = blockIdx.x * 32;
    const int by = blockIdx.y * 32;
    const int tx = threadIdx.x, ty = threadIdx.y;  // (32, 8)
#pragma unroll
    for (int i = 0; i < 4; ++i)
        tile[ty + i * 8][tx] = in[(long long)(by + ty + i * 8) * C + bx + tx];
    __syncthreads();
#pragma unroll
    for (int i = 0; i < 4; ++i)
        out[(long long)(bx + ty + i * 8) * R + by + tx] =
            f32_to_bf16_bits(tile[tx][ty + i * 8]);
}

// d_out[0:16] = t_span; traj[0] = y_init; ybf = bf16(y_init)
__global__ void init_kernel(const float* __restrict__ y0,
                            const float* __restrict__ tspan,
                            float* __restrict__ out,
                            unsigned short* __restrict__ ybf)
{
    const int i = blockIdx.x * blockDim.x + threadIdx.x;
    floatx4 v = ((const floatx4*)y0)[i];
    ((floatx4*)(out + TPTS))[i] = v;
    store_bf16x4(ybf + i * 4, v);
    if (blockIdx.x == 0 && threadIdx.x < TPTS) out[threadIdx.x] = tspan[threadIdx.x];
}

extern "C" void kernel_launch(void* const* d_in, const int* in_sizes, int n_in,
                              void* d_out, int out_size, void* d_ws, size_t ws_size,
                              hipStream_t stream)
{
    (void)in_sizes; (void)n_in; (void)out_size; (void)ws_size;
    const float* y0    = (const float*)d_in[0];
    const float* tspan = (const float*)d_in[1];
    const float* W1    = (const float*)d_in[2];
    const float* b1    = (const float*)d_in[3];
    const float* W2    = (const float*)d_in[4];
    const float* b2    = (const float*)d_in[5];
    float* out = (float*)d_out;

    char* ws = (char*)d_ws;
    unsigned short* W1T = (unsigned short*)(ws);                // [HID][DIM] bf16   8MB
    unsigned short* W2T = (unsigned short*)(ws + (8ll << 20));  // [DIM][HID] bf16   8MB
    unsigned short* Ybf = (unsigned short*)(ws + (16ll << 20)); // [BATCH][DIM] bf16 2MB
    unsigned short* Hbf = (unsigned short*)(ws + (18ll << 20)); // [BATCH][HID] bf16 8MB
    float* parts = (float*)(ws + (26ll << 20));                 // [4][BATCH][DIM]  16MB
    float* kacc  = (float*)(ws + (42ll << 20));                 // [BATCH][DIM]      4MB

    dim3 tb(32, 8);
    transpose_cast<<<dim3(HID / 32, DIM / 32), tb, 0, stream>>>(W1, W1T, DIM, HID);
    transpose_cast<<<dim3(DIM / 32, HID / 32), tb, 0, stream>>>(W2, W2T, HID, DIM);
    init_kernel<<<BATCH * DIM / 1024, 256, 0, stream>>>(y0, tspan, out, Ybf);

    float* traj = out + TPTS;
    for (int t = 0; t < TPTS - 1; ++t) {
        const float* ycur = traj + (long long)t * BATCH * DIM;
        float* ynext = traj + (long long)(t + 1) * BATCH * DIM;
        for (int e = 0; e < 4; ++e) {
            // H = tanh(Y @ W1 + b1)  -> bf16 [BATCH][HID]
            gemm_bt<1><<<dim3(HID / 128, BATCH / 128, 1), 256, 0, stream>>>(
                Ybf, W1T, b1, (void*)Hbf, DIM, DIM, HID, DIM, 0LL);
            // parts[z] = H[:, z*1024:+1024] @ W2[z*1024:+1024, :]  (split-K=4)
            gemm_bt<0><<<dim3(DIM / 128, BATCH / 128, 4), 256, 0, stream>>>(
                Hbf, W2T, nullptr, (void*)parts, HID, HID, DIM, HID / 4,
                (long long)BATCH * DIM);
            // k_e = sum(parts) + b2 ; RK4 update ; next Ybf
            combine<<<BATCH * DIM / 1024, 256, 0, stream>>>(
                parts, b2, ycur, tspan, t, e + 1, kacc, Ybf, ynext);
        }
    }
}

// Round 5
// 2602.701 us; speedup vs baseline: 2.6993x; 1.1141x over previous
//
#include <hip/hip_runtime.h>
#include <hip/hip_bf16.h>
#include <stdint.h>

#define BATCH 1024
#define DIM   1024
#define HID   4096
#define TPTS  16

typedef __attribute__((ext_vector_type(8))) short  short8;
typedef __attribute__((ext_vector_type(4))) float  floatx4;

__device__ __forceinline__ unsigned short f32_to_bf16_bits(float f) {
    union { float f; unsigned u; } v; v.f = f;
    return (unsigned short)((v.u + 0x7fffu + ((v.u >> 16) & 1u)) >> 16);
}

__device__ __forceinline__ void store_bf16x4(unsigned short* p, floatx4 v) {
    union { unsigned short u[4]; uint2 q; } pk;
    pk.u[0] = f32_to_bf16_bits(v[0]);
    pk.u[1] = f32_to_bf16_bits(v[1]);
    pk.u[2] = f32_to_bf16_bits(v[2]);
    pk.u[3] = f32_to_bf16_bits(v[3]);
    *(uint2*)p = pk.q;
}

// fast tanh: 1 - 2/(e^{2x}+1); saturates correctly for |x| large
__device__ __forceinline__ float fast_tanh(float x) {
    float e = __expf(2.0f * x);
    return 1.0f - 2.0f / (e + 1.0f);
}

// async 16B global -> LDS DMA. LDS dest = wave-uniform base + lane*16.
__device__ __forceinline__ void g2l16(const unsigned short* g, char* l) {
    __builtin_amdgcn_global_load_lds(
        (const __attribute__((address_space(1))) void*)g,
        (__attribute__((address_space(3))) void*)l, 16, 0, 0);
}

// C[M,N] tile = A[M,K] @ B[K,N]; A row-major bf16 (lda), Bt=B^T row-major (ldb).
// Tile 64(M) x 128(N), BK=64, 4 waves each 64x32, 24KB LDS,
// __launch_bounds__(256,2) -> 2 blocks/CU at 512-block grids (the barrier
// drain of one block overlaps the MFMA of the other — measured ~12us/gemm
// in R2 vs ~18us at 1 block/CU).
// MODE 1: Hbf = bf16(tanh(acc + bias[n])), coalesced store via LDS restage.
// MODE 0: fp32 split-K partial store (z = K-chunk). NO fences/atomics here —
//         device-scope fences inside the hot loop thrashed L2 (R2: 104us).
template<int MODE>
__global__ __launch_bounds__(256, 2)
void gemm_bt(const unsigned short* __restrict__ A,
             const unsigned short* __restrict__ Bt,
             const float* __restrict__ bias,
             void* __restrict__ Cout,
             int lda, int ldb, int ldc, int K, long long partStride)
{
    // sA: [64 rows][128B] = 8KB @0; sB: [128 rows][128B] = 16KB @8192.
    // Row = 8 chunks of 16B; chunk ch holds global k-chunk ch ^ (row & 7).
    __shared__ __align__(16) char smem[24576];
    char* sA = smem;
    char* sB = smem + 8192;

    const int tid  = threadIdx.x;
    const int wave = tid >> 6;
    const int lane = tid & 63;
    const int wn = wave * 32;          // wave col offset in tile
    const int lr = lane & 15;
    const int q  = lane >> 4;

    const int rowBase = blockIdx.y * 64;
    const int colBase = blockIdx.x * 128;
    const long long koff = (long long)blockIdx.z * K;

    // staging: 24KB / (256 thr * 16B) = 6 calls; j=0..1 -> sA, j=2..5 -> sB
    const unsigned short* gp[6];
    char* lp[6];
#pragma unroll
    for (int j = 0; j < 6; ++j) {
        const int p  = (j * 256 + tid) * 16;   // byte pos in 24KB
        const int pa = (j < 2) ? p : (p - 8192);
        const int row = pa >> 7;
        const int ch  = (pa >> 4) & 7;
        const int sc  = ch ^ (row & 7);
        if (j < 2)
            gp[j] = A + (long long)(rowBase + row) * lda + koff + sc * 8;
        else
            gp[j] = Bt + (long long)(colBase + row) * ldb + koff + sc * 8;
        lp[j] = smem + p;
    }

    floatx4 acc[4][2];
#pragma unroll
    for (int mi = 0; mi < 4; ++mi)
#pragma unroll
        for (int ni = 0; ni < 2; ++ni) {
            floatx4 z4 = {0.f, 0.f, 0.f, 0.f};
            acc[mi][ni] = z4;
        }

    const int xr = lr & 7;
    int aOff[4], bOff[2];
#pragma unroll
    for (int i = 0; i < 4; ++i) aOff[i] = (i * 16 + lr) * 128;
#pragma unroll
    for (int i = 0; i < 2; ++i) bOff[i] = (wn + i * 16 + lr) * 128;
    const int swz0 = ((0 + q) ^ xr) * 16;
    const int swz1 = ((4 + q) ^ xr) * 16;

    const int KB = K >> 6;  // BK = 64
    for (int kb = 0; kb < KB; ++kb) {
        if (kb) __syncthreads();
        const int kadv = kb * 64;
#pragma unroll
        for (int j = 0; j < 6; ++j)
            g2l16(gp[j] + kadv, lp[j]);
        __syncthreads();

        short8 af[4][2], bfr[2][2];
#pragma unroll
        for (int i = 0; i < 4; ++i) {
            af[i][0] = *(const short8*)(sA + aOff[i] + swz0);
            af[i][1] = *(const short8*)(sA + aOff[i] + swz1);
        }
#pragma unroll
        for (int i = 0; i < 2; ++i) {
            bfr[i][0] = *(const short8*)(sB + bOff[i] + swz0);
            bfr[i][1] = *(const short8*)(sB + bOff[i] + swz1);
        }
#pragma unroll
        for (int g = 0; g < 2; ++g)
#pragma unroll
            for (int mi = 0; mi < 4; ++mi)
#pragma unroll
                for (int ni = 0; ni < 2; ++ni)
                    acc[mi][ni] = __builtin_amdgcn_mfma_f32_16x16x32_bf16(
                        af[mi][g], bfr[ni][g], acc[mi][ni], 0, 0, 0);
    }

    if (MODE == 1) {
        __syncthreads();  // done reading sA/sB; reuse smem as sC
        float bias2[2];
#pragma unroll
        for (int ni = 0; ni < 2; ++ni)
            bias2[ni] = bias[colBase + wn + ni * 16 + lr];
        unsigned short* sC = (unsigned short*)smem;  // [64][136] bf16
#pragma unroll
        for (int mi = 0; mi < 4; ++mi)
#pragma unroll
            for (int ni = 0; ni < 2; ++ni)
#pragma unroll
                for (int r = 0; r < 4; ++r) {
                    const int row = mi * 16 + q * 4 + r;
                    const int col = wn + ni * 16 + lr;
                    sC[row * 136 + col] =
                        f32_to_bf16_bits(fast_tanh(acc[mi][ni][r] + bias2[ni]));
                }
        __syncthreads();
        unsigned short* C = (unsigned short*)Cout;
#pragma unroll
        for (int it = 0; it < 4; ++it) {
            const int row = it * 16 + (tid >> 4);
            const int cc  = (tid & 15) * 8;
            *(uint4*)(C + (long long)(rowBase + row) * ldc + colBase + cc) =
                *(const uint4*)(sC + row * 136 + cc);
        }
    } else {
        float* C = (float*)Cout + (long long)blockIdx.z * partStride;
#pragma unroll
        for (int mi = 0; mi < 4; ++mi)
#pragma unroll
            for (int ni = 0; ni < 2; ++ni) {
                const int r0 = rowBase + mi * 16 + q * 4;
                const int c  = colBase + wn + ni * 16 + lr;
#pragma unroll
                for (int r = 0; r < 4; ++r)
                    C[(long long)(r0 + r) * ldc + c] = acc[mi][ni][r];
            }
    }
}

// k = sum_z parts[z] + b2;  RK4 state update + bf16 cast of next matmul input.
__global__ void combine(const float* __restrict__ parts,
                        const float* __restrict__ b2,
                        const float* __restrict__ ycur,
                        const float* __restrict__ tspan,
                        int step, int mode,
                        float* __restrict__ kacc,
                        unsigned short* __restrict__ ybf,
                        float* __restrict__ ynext)
{
    const int i = blockIdx.x * blockDim.x + threadIdx.x;  // over BATCH*DIM/4
    const float h = tspan[step + 1] - tspan[step];
    const int NV = BATCH * DIM / 4;
    const floatx4* p = (const floatx4*)parts;
    floatx4 k = p[i] + p[i + NV] + p[i + 2 * NV] + p[i + 3 * NV];
    k = k + *(const floatx4*)(b2 + ((i * 4) & (DIM - 1)));
    floatx4 y = ((const floatx4*)ycur)[i];
    floatx4* ka = (floatx4*)kacc;
    if (mode == 1) {
        ka[i] = k;
        store_bf16x4(ybf + i * 4, y + (0.5f * h) * k);
    } else if (mode == 2) {
        ka[i] = ka[i] + 2.0f * k;
        store_bf16x4(ybf + i * 4, y + (0.5f * h) * k);
    } else if (mode == 3) {
        ka[i] = ka[i] + 2.0f * k;
        store_bf16x4(ybf + i * 4, y + h * k);
    } else {
        floatx4 yn = y + (h * (1.0f / 6.0f)) * (ka[i] + k);
        ((floatx4*)ynext)[i] = yn;
        store_bf16x4(ybf + i * 4, yn);
    }
}

// out[c][r] = bf16(in[r][c]); in is R x C fp32.
__global__ void transpose_cast(const float* __restrict__ in,
                               unsigned short* __restrict__ out, int R, int C)
{
    __shared__ float tile[32][33];
    const int bx = blockIdx.x * 32;
    const int by = blockIdx.y * 32;
    const int tx = threadIdx.x, ty = threadIdx.y;  // (32, 8)
#pragma unroll
    for (int i = 0; i < 4; ++i)
        tile[ty + i * 8][tx] = in[(long long)(by + ty + i * 8) * C + bx + tx];
    __syncthreads();
#pragma unroll
    for (int i = 0; i < 4; ++i)
        out[(long long)(bx + ty + i * 8) * R + by + tx] =
            f32_to_bf16_bits(tile[tx][ty + i * 8]);
}

// d_out[0:16] = t_span; traj[0] = y_init; ybf = bf16(y_init)
__global__ void init_kernel(const float* __restrict__ y0,
                            const float* __restrict__ tspan,
                            float* __restrict__ out,
                            unsigned short* __restrict__ ybf)
{
    const int i = blockIdx.x * blockDim.x + threadIdx.x;
    floatx4 v = ((const floatx4*)y0)[i];
    ((floatx4*)(out + TPTS))[i] = v;
    store_bf16x4(ybf + i * 4, v);
    if (blockIdx.x == 0 && threadIdx.x < TPTS) out[threadIdx.x] = tspan[threadIdx.x];
}

extern "C" void kernel_launch(void* const* d_in, const int* in_sizes, int n_in,
                              void* d_out, int out_size, void* d_ws, size_t ws_size,
                              hipStream_t stream)
{
    (void)in_sizes; (void)n_in; (void)out_size; (void)ws_size;
    const float* y0    = (const float*)d_in[0];
    const float* tspan = (const float*)d_in[1];
    const float* W1    = (const float*)d_in[2];
    const float* b1    = (const float*)d_in[3];
    const float* W2    = (const float*)d_in[4];
    const float* b2    = (const float*)d_in[5];
    float* out = (float*)d_out;

    char* ws = (char*)d_ws;
    unsigned short* W1T = (unsigned short*)(ws);                // [HID][DIM] bf16   8MB
    unsigned short* W2T = (unsigned short*)(ws + (8ll << 20));  // [DIM][HID] bf16   8MB
    unsigned short* Ybf = (unsigned short*)(ws + (16ll << 20)); // [BATCH][DIM] bf16 2MB
    unsigned short* Hbf = (unsigned short*)(ws + (18ll << 20)); // [BATCH][HID] bf16 8MB
    float* parts = (float*)(ws + (26ll << 20));                 // [4][BATCH][DIM]  16MB
    float* kacc  = (float*)(ws + (42ll << 20));                 // [BATCH][DIM]      4MB

    dim3 tb(32, 8);
    transpose_cast<<<dim3(HID / 32, DIM / 32), tb, 0, stream>>>(W1, W1T, DIM, HID);
    transpose_cast<<<dim3(DIM / 32, HID / 32), tb, 0, stream>>>(W2, W2T, HID, DIM);
    init_kernel<<<BATCH * DIM / 1024, 256, 0, stream>>>(y0, tspan, out, Ybf);

    float* traj = out + TPTS;
    for (int t = 0; t < TPTS - 1; ++t) {
        const float* ycur = traj + (long long)t * BATCH * DIM;
        float* ynext = traj + (long long)(t + 1) * BATCH * DIM;
        for (int e = 0; e < 4; ++e) {
            // H = tanh(Y @ W1 + b1) -> bf16 [BATCH][HID]; 512 blocks, 2/CU
            gemm_bt<1><<<dim3(HID / 128, BATCH / 64, 1), 256, 0, stream>>>(
                Ybf, W1T, b1, (void*)Hbf, DIM, DIM, HID, DIM, 0LL);
            // parts[z] = H[:,z*1024:+1024] @ W2[z*1024:+1024,:]; 512 blocks
            gemm_bt<0><<<dim3(DIM / 128, BATCH / 64, 4), 256, 0, stream>>>(
                Hbf, W2T, nullptr, (void*)parts, HID, HID, DIM, HID / 4,
                (long long)BATCH * DIM);
            // k_e = sum(parts) + b2 ; RK4 update ; next Ybf
            combine<<<BATCH * DIM / 1024, 256, 0, stream>>>(
                parts, b2, ycur, tspan, t, e + 1, kacc, Ybf, ynext);
        }
    }
}